// Round 2
// baseline (136.372 us; speedup 1.0000x reference)
//
#include <hip/hip_runtime.h>
#include <math.h>

#define OUT 260
#define TAPS 6
#define IMG_H 2048
#define IMG_W 2048
#define ROW_F (IMG_W * 3)            // 6144 floats per image row
#define IMG_TOTAL (IMG_H * ROW_F)    // total floats in image
#define NB 10
#define TH 0.8f
#define E3 (OUT * 3)                 // 780 elems per resampled row

typedef _Float16 half4v __attribute__((ext_vector_type(4)));

__device__ __forceinline__ float sincf(float x) {
    if (x == 0.0f) return 1.0f;
    float px = 3.14159265358979323846f * x;
    return __sinf(px) / px;
}

// ---------------- Pass 0: horizontal tap table per (box,q) ----------------
__global__ __launch_bounds__(256) void htaps_kernel(
    const float* __restrict__ boxes, float* __restrict__ wH, int* __restrict__ idxH)
{
    const int box = blockIdx.x;
    const float b1 = boxes[box * 4 + 1];
    const float b3 = boxes[box * 4 + 3];
    const int x0 = (int)(b1 * (float)IMG_W);
    const int x1 = (int)(b3 * (float)IMG_W);
    const int cw = max(x1 - x0, 1);
    const float scale = (float)cw / (float)OUT;

    for (int q = threadIdx.x; q < OUT; q += 256) {
        const float src = ((float)q + 0.5f) * scale - 0.5f;
        const int base = (int)floorf(src) - 2;
        float w[TAPS]; int id[TAPS];
        float s = 0.0f;
        #pragma unroll
        for (int k = 0; k < TAPS; ++k) {
            const int tap = base + k;
            const float d = src - (float)tap;
            const float wv = (fabsf(d) < 3.0f) ? sincf(d) * sincf(d * (1.0f / 3.0f)) : 0.0f;
            w[k] = wv; s += wv;
            int t = tap; t = t < 0 ? 0 : t; t = t > cw - 1 ? cw - 1 : t;
            id[k] = (x0 + t) * 3;   // global float index of pixel triple start
        }
        const float inv = 1.0f / s;
        const int o = (box * OUT + q) * TAPS;
        #pragma unroll
        for (int k = 0; k < TAPS; ++k) { wH[o + k] = w[k] * inv; idxH[o + k] = id[k]; }
    }
}

// ------- Pass 1: per (box,p,a): stage source row in LDS, horizontal resample -------
__global__ __launch_bounds__(256) void hresample_kernel(
    const float* __restrict__ boxes, const float* __restrict__ img,
    const float* __restrict__ wH, const int* __restrict__ idxH,
    _Float16* __restrict__ tmp)
{
    const int a   = blockIdx.x;   // tap 0..5
    const int p   = blockIdx.y;   // output row 0..259
    const int box = blockIdx.z;

    const float b0 = boxes[box * 4 + 0];
    const float b1 = boxes[box * 4 + 1];
    const float b2 = boxes[box * 4 + 2];
    const float b3 = boxes[box * 4 + 3];
    const int y0 = (int)(b0 * (float)IMG_H);
    const int x0 = (int)(b1 * (float)IMG_W);
    const int y1 = (int)(b2 * (float)IMG_H);
    const int x1 = (int)(b3 * (float)IMG_W);
    const int ch = max(y1 - y0, 1);
    const int cw = max(x1 - x0, 1);

    // source row for this (p, a)
    const float srch = ((float)p + 0.5f) * ((float)ch / (float)OUT) - 0.5f;
    const int baseh = (int)floorf(srch) - 2;
    int t = baseh + a; t = t < 0 ? 0 : t; t = t > ch - 1 ? ch - 1 : t;
    const int r = t + y0;

    // stage row span [start_f, end_f) into LDS (16B-aligned start)
    const int start_f = (x0 * 3) & ~3;
    const int end_f   = (x0 + cw) * 3;
    const int n_f     = end_f - start_f;

    __shared__ float lds[6152];
    const size_t gbase = (size_t)r * ROW_F + start_f;
    for (int j4 = threadIdx.x * 4; j4 < n_f; j4 += 256 * 4) {
        const size_t g = gbase + (size_t)j4;
        if (g + 3 < (size_t)IMG_TOTAL) {
            const float4 v = *(const float4*)(img + g);
            lds[j4 + 0] = v.x; lds[j4 + 1] = v.y; lds[j4 + 2] = v.z; lds[j4 + 3] = v.w;
        } else {
            #pragma unroll
            for (int i = 0; i < 4; ++i) {
                size_t gi = g + i; if (gi > (size_t)(IMG_TOTAL - 1)) gi = IMG_TOTAL - 1;
                lds[j4 + i] = img[gi];
            }
        }
    }
    __syncthreads();

    const size_t tbase = (((size_t)(box * OUT + p)) * TAPS + a) * E3;
    for (int q = threadIdx.x; q < OUT; q += 256) {
        const int o = (box * OUT + q) * TAPS;
        float acc0 = 0.0f, acc1 = 0.0f, acc2 = 0.0f;
        #pragma unroll
        for (int k = 0; k < TAPS; ++k) {
            const float w = wH[o + k];
            const int   li = idxH[o + k] - start_f;
            acc0 = fmaf(w, lds[li + 0], acc0);
            acc1 = fmaf(w, lds[li + 1], acc1);
            acc2 = fmaf(w, lds[li + 2], acc2);
        }
        tmp[tbase + q * 3 + 0] = (_Float16)acc0;
        tmp[tbase + q * 3 + 1] = (_Float16)acc1;
        tmp[tbase + q * 3 + 2] = (_Float16)acc2;
    }
}

// ------- Pass 2: per (box,p): vertical combine of 6 fp16 rows + mask -------
__global__ __launch_bounds__(256) void vresample_kernel(
    const float* __restrict__ scores, const float* __restrict__ boxes,
    const _Float16* __restrict__ tmp, float* __restrict__ out)
{
    const int p   = blockIdx.x;
    const int box = blockIdx.y;

    const float b0 = boxes[box * 4 + 0];
    const float b1 = boxes[box * 4 + 1];
    const float b2 = boxes[box * 4 + 2];
    const float b3 = boxes[box * 4 + 3];
    const int y0 = (int)(b0 * (float)IMG_H);
    const int y1 = (int)(b2 * (float)IMG_H);
    const int ch = max(y1 - y0, 1);

    const bool valid = (scores[0] >= TH) && (scores[box] >= TH)
                    && (b1 >= 0.0f) && (b3 <= 1.0f);
    const float vmask = valid ? 1.0f : 0.0f;

    // vertical weights (block-uniform)
    float wh[TAPS];
    {
        const float src = ((float)p + 0.5f) * ((float)ch / (float)OUT) - 0.5f;
        const int base = (int)floorf(src) - 2;
        float s = 0.0f;
        #pragma unroll
        for (int k = 0; k < TAPS; ++k) {
            const float d = src - (float)(base + k);
            const float w = (fabsf(d) < 3.0f) ? sincf(d) * sincf(d * (1.0f / 3.0f)) : 0.0f;
            wh[k] = w; s += w;
        }
        const float inv = 1.0f / s;
        #pragma unroll
        for (int k = 0; k < TAPS; ++k) wh[k] *= inv;
    }

    const size_t tbase = ((size_t)(box * OUT + p)) * TAPS * E3;
    const size_t obase = ((size_t)(box * OUT + p)) * E3;

    const int j = threadIdx.x;
    if (j < E3 / 4) {                      // 195 float4 groups of 780
        const int e = j * 4;
        float4 acc = make_float4(0.f, 0.f, 0.f, 0.f);
        #pragma unroll
        for (int k = 0; k < TAPS; ++k) {
            const half4v v = *(const half4v*)(tmp + tbase + (size_t)k * E3 + e);
            acc.x = fmaf(wh[k], (float)v.x, acc.x);
            acc.y = fmaf(wh[k], (float)v.y, acc.y);
            acc.z = fmaf(wh[k], (float)v.z, acc.z);
            acc.w = fmaf(wh[k], (float)v.w, acc.w);
        }
        acc.x *= vmask; acc.y *= vmask; acc.z *= vmask; acc.w *= vmask;
        *(float4*)(out + obase + e) = acc;
    }
}

// ---------------- Fallback: round-1 fused gather kernel ----------------
__global__ __launch_bounds__(256) void crop_resize_fallback(
    const float* __restrict__ scores, const float* __restrict__ boxes,
    const float* __restrict__ img, float* __restrict__ out)
{
    const int p = blockIdx.x;
    const int box = blockIdx.y;
    const float b0 = boxes[box * 4 + 0], b1 = boxes[box * 4 + 1];
    const float b2 = boxes[box * 4 + 2], b3 = boxes[box * 4 + 3];
    const int y0 = (int)(b0 * (float)IMG_H), x0 = (int)(b1 * (float)IMG_W);
    const int y1 = (int)(b2 * (float)IMG_H), x1 = (int)(b3 * (float)IMG_W);
    const int ch = max(y1 - y0, 1), cw = max(x1 - x0, 1);
    const bool valid = (scores[0] >= TH) && (scores[box] >= TH) && (b1 >= 0.0f) && (b3 <= 1.0f);
    const float vmask = valid ? 1.0f : 0.0f;

    float wh[6]; int ih[6];
    {
        const float src = ((float)p + 0.5f) * ((float)ch / (float)OUT) - 0.5f;
        const int base = (int)floorf(src) - 2;
        float s = 0.0f;
        #pragma unroll
        for (int a = 0; a < 6; ++a) {
            const int tap = base + a;
            const float d = src - (float)tap;
            const float w = (fabsf(d) < 3.0f) ? sincf(d) * sincf(d * (1.0f / 3.0f)) : 0.0f;
            wh[a] = w; s += w;
            int tt = tap; tt = tt < 0 ? 0 : tt; tt = tt > ch - 1 ? ch - 1 : tt;
            ih[a] = tt + y0;
        }
        const float inv = 1.0f / s;
        #pragma unroll
        for (int a = 0; a < 6; ++a) wh[a] *= inv;
    }
    const float wscale = (float)cw / (float)OUT;
    for (int q = threadIdx.x; q < OUT; q += blockDim.x) {
        float ww[6]; int iw[6];
        const float src = ((float)q + 0.5f) * wscale - 0.5f;
        const int base = (int)floorf(src) - 2;
        float s = 0.0f;
        #pragma unroll
        for (int b = 0; b < 6; ++b) {
            const int tap = base + b;
            const float d = src - (float)tap;
            const float w = (fabsf(d) < 3.0f) ? sincf(d) * sincf(d * (1.0f / 3.0f)) : 0.0f;
            ww[b] = w; s += w;
            int tt = tap; tt = tt < 0 ? 0 : tt; tt = tt > cw - 1 ? cw - 1 : tt;
            iw[b] = (tt + x0) * 3;
        }
        const float inv = 1.0f / s;
        #pragma unroll
        for (int b = 0; b < 6; ++b) ww[b] *= inv;
        float acc0 = 0, acc1 = 0, acc2 = 0;
        #pragma unroll
        for (int a = 0; a < 6; ++a) {
            const float* row = img + (size_t)ih[a] * ROW_F;
            float r0 = 0, r1 = 0, r2 = 0;
            #pragma unroll
            for (int b = 0; b < 6; ++b) {
                const float* px = row + iw[b];
                r0 = fmaf(ww[b], px[0], r0);
                r1 = fmaf(ww[b], px[1], r1);
                r2 = fmaf(ww[b], px[2], r2);
            }
            acc0 = fmaf(wh[a], r0, acc0);
            acc1 = fmaf(wh[a], r1, acc1);
            acc2 = fmaf(wh[a], r2, acc2);
        }
        const size_t o = (((size_t)box * OUT + p) * OUT + q) * 3;
        out[o + 0] = acc0 * vmask; out[o + 1] = acc1 * vmask; out[o + 2] = acc2 * vmask;
    }
}

extern "C" void kernel_launch(void* const* d_in, const int* in_sizes, int n_in,
                              void* d_out, int out_size, void* d_ws, size_t ws_size,
                              hipStream_t stream) {
    const float* scores = (const float*)d_in[0];   // (100,)
    const float* boxes  = (const float*)d_in[1];   // (100,4)
    const float* img    = (const float*)d_in[2];   // (1,2048,2048,3)
    float* out = (float*)d_out;                    // (10,260,260,3)

    // workspace layout: [ tmp fp16 (10*260*6*780) | wH (10*260*6 f32) | idxH (10*260*6 i32) ]
    const size_t tmp_bytes = (size_t)NB * OUT * TAPS * E3 * sizeof(_Float16); // 24,336,000
    const size_t tab_elems = (size_t)NB * OUT * TAPS;                          // 15,600
    const size_t need = tmp_bytes + tab_elems * (sizeof(float) + sizeof(int));

    if (ws_size < need) {
        crop_resize_fallback<<<dim3(OUT, NB), dim3(256), 0, stream>>>(scores, boxes, img, out);
        return;
    }

    _Float16* tmp = (_Float16*)d_ws;
    float* wH  = (float*)((char*)d_ws + tmp_bytes);
    int*   idxH = (int*)((char*)d_ws + tmp_bytes + tab_elems * sizeof(float));

    htaps_kernel<<<dim3(NB), dim3(256), 0, stream>>>(boxes, wH, idxH);
    hresample_kernel<<<dim3(TAPS, OUT, NB), dim3(256), 0, stream>>>(boxes, img, wH, idxH, tmp);
    vresample_kernel<<<dim3(OUT, NB), dim3(256), 0, stream>>>(scores, boxes, tmp, out);
}